// Round 6
// baseline (89.375 us; speedup 1.0000x reference)
//
#include <hip/hip_runtime.h>
#include <hip/hip_bf16.h>

typedef __bf16 bf16x8 __attribute__((ext_vector_type(8)));
typedef __bf16 bf16x4 __attribute__((ext_vector_type(4)));
typedef float  f32x4  __attribute__((ext_vector_type(4)));

static constexpr int E    = 1965;   // J*D + J*3
static constexpr int KF   = 1920;   // J*D
static constexpr int NJ   = 15;
static constexpr int NCLS = 68;
static constexpr int NPAD = 80;     // 5 tiles of 16
static constexpr int NT   = 5;
static constexpr int NS   = 60;     // k-steps of 32

static constexpr int CH   = 12;     // chunks
static constexpr int KPC  = 5;      // k-steps per chunk
static constexpr int CCOL = 160;    // fp32 cols per chunk
static constexpr int SEGC = 40;     // 4-float segs per chunk
static constexpr int NBUF = 4;      // LDS chunk buffers (3-deep pipeline + compute)

// ws layout:
//   pnf: [NT][NS][64][8] __bf16  = 307200 B
//   pa : [NPAD][45] float        = 14400 B
static constexpr size_t PNF_BYTES = (size_t)NT * NS * 64 * 8 * 2;

// ---------------- kernel 1: normalize W -> bf16 fragments + angle extract ----
__global__ __launch_bounds__(256) void prep_kernel(const float* __restrict__ W,
                                                   __bf16* __restrict__ pnf,
                                                   float* __restrict__ pa) {
    const int n = blockIdx.x;      // 0..79
    const int t = threadIdx.x;     // 0..255
    float v[8];
    float ss = 0.f;
    if (n < NCLS && t < 240) {
        const float* src = W + (size_t)n * E + 8 * t;
        #pragma unroll
        for (int i = 0; i < 8; ++i) { v[i] = src[i]; ss += v[i] * v[i]; }
    } else {
        #pragma unroll
        for (int i = 0; i < 8; ++i) v[i] = 0.f;
    }
    #pragma unroll
    for (int off = 32; off >= 1; off >>= 1) ss += __shfl_xor(ss, off);
    __shared__ float rbuf[4];
    if ((t & 63) == 0) rbuf[t >> 6] = ss;
    __syncthreads();
    const float total = rbuf[0] + rbuf[1] + rbuf[2] + rbuf[3];
    const float rnorm = 1.f / fmaxf(sqrtf(total), 1e-12f);

    if (t < 240) {
        bf16x8 o;
        #pragma unroll
        for (int i = 0; i < 8; ++i) o[i] = (__bf16)(v[i] * rnorm);
        const int s = t >> 2, g = t & 3;
        const int lane = (n & 15) + 16 * g;
        const size_t off = (((size_t)(n >> 4) * NS + s) * 64 + lane) * 8;
        *(bf16x8*)(pnf + off) = o;
    }
    if (t < 45) {
        pa[n * 45 + t] = (n < NCLS) ? W[(size_t)n * E + KF + t] : 0.f;
    }
}

// ---------------- kernel 2: fused GEMM + norm + angle softmax ----------------
__global__ __launch_bounds__(320) void cos_kernel(const float* __restrict__ emb,
                                                  const __bf16* __restrict__ pnf,
                                                  const float* __restrict__ pa,
                                                  float* __restrict__ out) {
    // chunk buffers: [seg][row][4 floats]; DMA dest linear in lane order.
    __shared__ f32x4  Abuf[NBUF][SEGC][16];   // 40,960 B
    __shared__ __bf16 pal[NPAD][52];          //  8,320 B
    __shared__ float  xa[16][48];             //  3,072 B  -> 52,352 B total

    const int tid = threadIdx.x;
    const int m0  = blockIdx.x * 16;
    const int w   = tid >> 6;    // wave 0..4 (= N-tile)
    const int l   = tid & 63;
    const int lr  = l & 15;      // row within tile / B col
    const int lg  = l >> 4;      // k-group

    // ---- angle staging (completed before first barrier via lgkmcnt(0)) ----
    for (int idx = tid; idx < 16 * 45; idx += 320) {
        const int r = idx / 45, c = idx - r * 45;
        xa[r][c] = emb[(size_t)(m0 + r) * E + KF + c];
    }
    for (int idx = tid; idx < NPAD * 45; idx += 320) {
        const int n = idx / 45, c = idx - n * 45;
        pal[n][c] = (__bf16)pa[idx];
    }

    // ---- DMA issue: 2 x global_load_lds per wave per chunk ----
    // lane -> seg = 8w + 4i + lg, row = lr; LDS dest linear (1 KB per instr)
    const float* gbase = emb + (size_t)(m0 + lr) * E + 4 * (8 * w + lg);
    #define ISSUE(c)                                                                    \
        {                                                                               \
            _Pragma("unroll")                                                           \
            for (int i_ = 0; i_ < 2; ++i_)                                              \
                __builtin_amdgcn_global_load_lds(                                       \
                    (const __attribute__((address_space(1))) void*)(gbase + (c) * CCOL + 16 * i_), \
                    (__attribute__((address_space(3))) void*)&Abuf[(c) & 3][8 * w + 4 * i_][0],    \
                    16, 0, 0);                                                          \
        }

    const bf16x8* bp = (const bf16x8*)pnf + (size_t)w * NS * 64 + l;

    f32x4 acc[NJ];
    #pragma unroll
    for (int j = 0; j < NJ; ++j) acc[j] = f32x4{0.f, 0.f, 0.f, 0.f};
    float ssq = 0.f;

    bf16x8 bfr[2][KPC];                       // 2 banks, statically indexed
    #pragma unroll
    for (int j = 0; j < KPC; ++j) bfr[0][j] = bp[j * 64];

    // prologue: 3 chunks in flight; wait chunk 0 (only DMA1,2 = 4 newer DMA ops)
    ISSUE(0); ISSUE(1); ISSUE(2);
    asm volatile("s_waitcnt vmcnt(4) lgkmcnt(0)" ::: "memory");
    __builtin_amdgcn_sched_barrier(0);

    #pragma unroll
    for (int c = 0; c < CH; ++c) {
        __builtin_amdgcn_s_barrier();          // buf[(c-1)&3] readers done + chunk c visible
        if (c + 3 < CH) ISSUE(c + 3);

        // ---- compute chunk c (5 k-steps) ----
        #pragma unroll
        for (int j = 0; j < KPC; ++j) {
            const int s0 = 8 * j + 2 * lg;
            const f32x4 alo = Abuf[c & 3][s0][lr];
            const f32x4 ahi = Abuf[c & 3][s0 + 1][lr];
            bf16x8 af;
            #pragma unroll
            for (int q = 0; q < 4; ++q) {
                ssq += alo[q] * alo[q] + ahi[q] * ahi[q];
                af[q]     = (__bf16)alo[q];
                af[4 + q] = (__bf16)ahi[q];
            }
            const int gk = c * KPC + j;
            acc[gk >> 2] = __builtin_amdgcn_mfma_f32_16x16x32_bf16(af, bfr[c & 1][j], acc[gk >> 2], 0, 0, 0);
        }

        // ---- end-of-iter wait: retire chunk c+1 (only DMA c+2,c+3 newer) ----
        if (c <= CH - 4)      { asm volatile("s_waitcnt vmcnt(4)" ::: "memory"); }
        else if (c == CH - 3) { asm volatile("s_waitcnt vmcnt(2)" ::: "memory"); }
        else if (c == CH - 2) { asm volatile("s_waitcnt vmcnt(0)" ::: "memory"); }
        __builtin_amdgcn_sched_barrier(0);

        // ---- B prefetch for chunk c+1 (after wait: keeps vmcnt queue clean) ----
        if (c + 1 < CH) {
            #pragma unroll
            for (int j = 0; j < KPC; ++j)
                bfr[(c + 1) & 1][j] = bp[((c + 1) * KPC + j) * 64];
        }
    }
    #undef ISSUE

    // ---- row norms: redundant per wave; pure shfl reduce ----
    ssq += __shfl_xor(ssq, 16);
    ssq += __shfl_xor(ssq, 32);               // full row-lr sum in every lane

    const int r0  = lg * 4;       // C/D: row = (lane>>4)*4 + reg, col = lane&15
    const int col = w * 16 + lr;

    float rn[4];
    #pragma unroll
    for (int r = 0; r < 4; ++r)
        rn[r] = 240.f / fmaxf(sqrtf(__shfl(ssq, r0 + r)), 1e-12f);   // 16*15/norm

    // ---- angle softmax epilogue ----
    float pr[45];
    #pragma unroll
    for (int q = 0; q < 12; ++q) {
        const bf16x4 pv = *(const bf16x4*)&pal[col][4 * q];
        #pragma unroll
        for (int e = 0; e < 4; ++e)
            if (4 * q + e < 45) pr[4 * q + e] = (float)pv[e];
    }

    float num[4] = {0.f, 0.f, 0.f, 0.f};
    float den[4] = {0.f, 0.f, 0.f, 0.f};
    #pragma unroll
    for (int r = 0; r < 4; ++r) {
        f32x4 xr[12];
        #pragma unroll
        for (int q = 0; q < 12; ++q)
            xr[q] = *(const f32x4*)&xa[r0 + r][4 * q];
        #pragma unroll
        for (int j = 0; j < NJ; ++j) {
            const float d0 = xr[(3 * j + 0) >> 2][(3 * j + 0) & 3] - pr[3 * j + 0];
            const float d1 = xr[(3 * j + 1) >> 2][(3 * j + 1) & 3] - pr[3 * j + 1];
            const float d2 = xr[(3 * j + 2) >> 2][(3 * j + 2) & 3] - pr[3 * j + 2];
            const float dist = sqrtf(d0 * d0 + d1 * d1 + d2 * d2);
            const float e = __expf(dist * 0.005f);   // exponents in [0, ~0.05]
            den[r] += e;
            num[r] += e * acc[j][r];
        }
    }

    if (col < NCLS) {
        #pragma unroll
        for (int r = 0; r < 4; ++r)
            out[(size_t)(m0 + r0 + r) * NCLS + col] = rn[r] * num[r] / den[r];
    }
}

extern "C" void kernel_launch(void* const* d_in, const int* in_sizes, int n_in,
                              void* d_out, int out_size, void* d_ws, size_t ws_size,
                              hipStream_t stream) {
    const float* emb = (const float*)d_in[0];
    const float* W   = (const float*)d_in[1];
    float* out = (float*)d_out;
    __bf16* pnf = (__bf16*)d_ws;
    float*  pa  = (float*)((char*)d_ws + PNF_BYTES);
    const int B = in_sizes[0] / E;           // 16384

    prep_kernel<<<NPAD, 256, 0, stream>>>(W, pnf, pa);
    cos_kernel<<<B / 16, 320, 0, stream>>>(emb, pnf, pa, out);
}

// Round 7
// 81.015 us; speedup vs baseline: 1.1032x; 1.1032x over previous
//
#include <hip/hip_runtime.h>
#include <hip/hip_bf16.h>

typedef __bf16 bf16x8 __attribute__((ext_vector_type(8)));
typedef float  f32x4  __attribute__((ext_vector_type(4)));

static constexpr int E    = 1965;   // J*D + J*3
static constexpr int KF   = 1920;   // J*D
static constexpr int NJ   = 15;
static constexpr int NCLS = 68;
static constexpr int NPAD = 80;     // 5 tiles of 16
static constexpr int NT   = 5;
static constexpr int NS   = 60;     // k-steps of 32

// ws layout:
//   pnf: [NT][NS][64][8] __bf16  = 307200 B
//   pa : [NPAD][45] float        = 14400 B
static constexpr size_t PNF_BYTES = (size_t)NT * NS * 64 * 8 * 2;

// ---------------- kernel 1: normalize W -> bf16 fragments + angle extract ----
__global__ __launch_bounds__(256) void prep_kernel(const float* __restrict__ W,
                                                   __bf16* __restrict__ pnf,
                                                   float* __restrict__ pa) {
    const int n = blockIdx.x;      // 0..79
    const int t = threadIdx.x;     // 0..255
    float v[8];
    float ss = 0.f;
    if (n < NCLS && t < 240) {
        const float* src = W + (size_t)n * E + 8 * t;
        #pragma unroll
        for (int i = 0; i < 8; ++i) { v[i] = src[i]; ss += v[i] * v[i]; }
    } else {
        #pragma unroll
        for (int i = 0; i < 8; ++i) v[i] = 0.f;
    }
    #pragma unroll
    for (int off = 32; off >= 1; off >>= 1) ss += __shfl_xor(ss, off);
    __shared__ float rbuf[4];
    if ((t & 63) == 0) rbuf[t >> 6] = ss;
    __syncthreads();
    const float total = rbuf[0] + rbuf[1] + rbuf[2] + rbuf[3];
    const float rnorm = 1.f / fmaxf(sqrtf(total), 1e-12f);

    if (t < 240) {
        bf16x8 o;
        #pragma unroll
        for (int i = 0; i < 8; ++i) o[i] = (__bf16)(v[i] * rnorm);
        const int s = t >> 2, g = t & 3;
        const int lane = (n & 15) + 16 * g;
        const size_t off = (((size_t)(n >> 4) * NS + s) * 64 + lane) * 8;
        *(bf16x8*)(pnf + off) = o;
    }
    if (t < 45) {
        pa[n * 45 + t] = (n < NCLS) ? W[(size_t)n * E + KF + t] : 0.f;
    }
}

// ---------------- kernel 2: barrier-free fused GEMM + norm + angle softmax ----
// 5 independent waves per block; wave = (16 rows, one 16-col N-tile, full K).
// A-fragments built by in-register shfl transpose; no __syncthreads anywhere.
__global__ __launch_bounds__(320, 4) void cos_kernel(const float* __restrict__ emb,
                                                     const __bf16* __restrict__ pnf,
                                                     const float* __restrict__ pa,
                                                     float* __restrict__ out) {
    __shared__ float xa[NT][16][48];          // per-wave private; 15,360 B

    const int tid = threadIdx.x;
    const int w   = tid >> 6;     // wave / N-tile 0..4
    const int l   = tid & 63;
    const int lr  = l & 15;       // fragment row (A) / col (B,C)
    const int lg  = l >> 4;       // fragment k-group / C row-group
    const int m0  = blockIdx.x * 16;

    // load role: lane covers row r = l/4, col-class p = l%4 (cols 8p..8p+8 per k-step)
    const int r = l >> 2;
    const int p = l & 3;

    // ---- per-wave xa staging (same-wave lgkm ordering; no barrier) ----
    {
        const float* src = emb + (size_t)(m0 + r) * E + KF;
        if (p < 3) {
            #pragma unroll
            for (int q = 0; q < 3; ++q) {
                f32x4 v;
                __builtin_memcpy(&v, src + 12 * p + 4 * q, 16);
                *(f32x4*)&xa[w][r][12 * p + 4 * q] = v;
            }
        } else {
            f32x4 v;
            __builtin_memcpy(&v, src + 36, 16);
            *(f32x4*)&xa[w][r][36] = v;
            __builtin_memcpy(&v, src + 40, 16);
            *(f32x4*)&xa[w][r][40] = v;
            xa[w][r][44] = src[44];
        }
    }

    // ---- main loop: load -> ssq -> cvt -> shfl-transpose -> MFMA ----
    const float*  ap   = emb + (size_t)(m0 + r) * E + 8 * p;
    const bf16x8* bp   = (const bf16x8*)pnf + (size_t)w * NS * 64 + l;
    const int     srcl = 4 * lr + lg;     // transpose source lane (fixed)

    f32x4 acc[NJ];
    #pragma unroll
    for (int j = 0; j < NJ; ++j) acc[j] = f32x4{0.f, 0.f, 0.f, 0.f};
    float ssq = 0.f;

    #pragma unroll
    for (int s = 0; s < NS; ++s) {
        f32x4 alo, ahi;
        __builtin_memcpy(&alo, ap + 32 * s,     16);
        __builtin_memcpy(&ahi, ap + 32 * s + 4, 16);
        const bf16x8 b = bp[s * 64];

        union { bf16x8 h; int u[4]; } pk, tf;
        #pragma unroll
        for (int q = 0; q < 4; ++q) {
            ssq += alo[q] * alo[q] + ahi[q] * ahi[q];
            pk.h[q]     = (__bf16)alo[q];
            pk.h[4 + q] = (__bf16)ahi[q];
        }
        #pragma unroll
        for (int q = 0; q < 4; ++q)
            tf.u[q] = __shfl(pk.u[q], srcl);   // lane gets row lr, cols 8lg..+8

        acc[s >> 2] = __builtin_amdgcn_mfma_f32_16x16x32_bf16(tf.h, b, acc[s >> 2], 0, 0, 0);
    }

    // ---- row norms: lanes 4r..4r+3 hold row r partials ----
    ssq += __shfl_xor(ssq, 1);
    ssq += __shfl_xor(ssq, 2);                // lanes 4r+* : full row-r sum

    float rn[4];
    #pragma unroll
    for (int t = 0; t < 4; ++t)               // C row (4lg+t) total sits in lane 16lg+4t
        rn[t] = 240.f / fmaxf(sqrtf(__shfl(ssq, 16 * lg + 4 * t)), 1e-12f);

    // ---- angle softmax epilogue ----
    const int col = 16 * w + lr;
    const float* pav = pa + col * 45;         // L1/L2-hot (14.4 KB total)

    float num[4] = {0.f, 0.f, 0.f, 0.f};
    float den[4] = {0.f, 0.f, 0.f, 0.f};
    #pragma unroll
    for (int j = 0; j < NJ; ++j) {
        const float p0 = pav[3 * j + 0];
        const float p1 = pav[3 * j + 1];
        const float p2 = pav[3 * j + 2];
        #pragma unroll
        for (int t = 0; t < 4; ++t) {
            const float d0 = xa[w][4 * lg + t][3 * j + 0] - p0;
            const float d1 = xa[w][4 * lg + t][3 * j + 1] - p1;
            const float d2 = xa[w][4 * lg + t][3 * j + 2] - p2;
            const float dist = sqrtf(d0 * d0 + d1 * d1 + d2 * d2);
            const float e = __expf(dist * 0.005f);   // exponents in [0, ~0.05]
            den[t] += e;
            num[t] += e * acc[j][t];
        }
    }

    if (col < NCLS) {
        #pragma unroll
        for (int t = 0; t < 4; ++t)
            out[(size_t)(m0 + 4 * lg + t) * NCLS + col] = rn[t] * num[t] / den[t];
    }
}

extern "C" void kernel_launch(void* const* d_in, const int* in_sizes, int n_in,
                              void* d_out, int out_size, void* d_ws, size_t ws_size,
                              hipStream_t stream) {
    const float* emb = (const float*)d_in[0];
    const float* W   = (const float*)d_in[1];
    float* out = (float*)d_out;
    __bf16* pnf = (__bf16*)d_ws;
    float*  pa  = (float*)((char*)d_ws + PNF_BYTES);
    const int B = in_sizes[0] / E;           // 16384

    prep_kernel<<<NPAD, 256, 0, stream>>>(W, pnf, pa);
    cos_kernel<<<B / 16, 320, 0, stream>>>(emb, pnf, pa, out);
}